// Round 7
// baseline (5632.583 us; speedup 1.0000x reference)
//
#include <hip/hip_runtime.h>

constexpr int B = 32, L = 1024, D = 512, H = 512;

// ---- LDS byte offsets ----
// A operands: [16 rows][512 k] bf16, rows 8..15 permanently zero.
constexpr int AH_HI = 0;
constexpr int AH_LO = 16384;
constexpr int AX_HI = 32768;
constexpr int AX_LO = 49152;
// B operands: [2 tiles][16 n][512 k] bf16. BH tile0=[Whz|Whr] tile1=[Whh|0];
// BX tile0=[Wxz|Wxr] tile1=[0|Wxh].
constexpr int BH_OFF = 65536;
constexpr int BX_OFF = 98304;
// C partials: [4 waves][2 tiles][8 m][17] f32
constexpr int CB_OFF = 131072;
constexpr size_t SMEM_BYTES = 135424;   // 132.25 KiB (proven territory)

typedef __attribute__((ext_vector_type(8))) short short8v;
typedef __attribute__((ext_vector_type(4))) float f32x4;
using ull = unsigned long long;

__device__ __forceinline__ unsigned short f2bf(float f) {   // RNE f32->bf16
    unsigned u = __float_as_uint(f);
    return (unsigned short)((u + 0x7FFFu + ((u >> 16) & 1u)) >> 16);
}
__device__ __forceinline__ float bf2f(unsigned short b) {
    return __uint_as_float((unsigned)b << 16);
}
// XOR-swizzled byte address within a [row][1024B] tile
__device__ __forceinline__ int aswz(int row, int kbyte) {
    return row * 1024 + (kbyte ^ ((row & 7) << 4));
}
// 8 floats -> packed bf16 hi/lo uint4s
__device__ __forceinline__ void split8(const float* v, uint4& phi, uint4& plo) {
    unsigned hi[8], lo[8];
#pragma unroll
    for (int i = 0; i < 8; ++i) {
        const unsigned short h = f2bf(v[i]);
        hi[i] = h;
        lo[i] = f2bf(v[i] - bf2f(h));
    }
    phi = make_uint4(hi[0] | (hi[1] << 16), hi[2] | (hi[3] << 16),
                     hi[4] | (hi[5] << 16), hi[6] | (hi[7] << 16));
    plo = make_uint4(lo[0] | (lo[1] << 16), lo[2] | (lo[3] << 16),
                     lo[4] | (lo[5] << 16), lo[6] | (lo[7] << 16));
}

// Record: high dword = (bf16_hi << 16) | bf16_lo of h value; low dword = stamp.
// hgq[(((parity*4 + ring)*64 + member)*64 + batch*8 + feat)]  (256 KiB total)

__global__ __launch_bounds__(256, 1)
void gru_sys(const float* __restrict__ x, const float* __restrict__ h0,
             const float* __restrict__ Wxz, const float* __restrict__ Whz,
             const float* __restrict__ bz,
             const float* __restrict__ Wxr, const float* __restrict__ Whr,
             const float* __restrict__ br,
             const float* __restrict__ Wxh, const float* __restrict__ Whh,
             const float* __restrict__ bh,
             float* __restrict__ out, ull* __restrict__ hgq)
{
    extern __shared__ char smem[];

    const int tid = threadIdx.x;
    const int bid = blockIdx.x;
    // XCD-affinity remap (R5, kept): ring g occupies XCD residues {g, g+4}
    const int g  = bid & 3;          // ring: batches g*8 .. g*8+7
    const int fc = bid >> 2;         // member: features fc*8 .. +7
    const int F0 = fc * 8;

    // ---- zero all LDS (A pad rows + B zero-blocks must stay zero) ----
    for (int i = tid; i < (int)(SMEM_BYTES / 16); i += 256)
        *(uint4*)(smem + i * 16) = make_uint4(0, 0, 0, 0);
    __syncthreads();

    // ---- one-time weight staging: bf16, swizzled [n][k] fragments ----
    {
        const float* WSET[2][3] = {{Whz, Whr, Whh}, {Wxz, Wxr, Wxh}};
        const int TB[2][3][2] = {{{0,0},{0,8},{1,0}}, {{0,0},{0,8},{1,8}}};
        for (int s = 0; s < 2; ++s) {
            const int bbase = (s == 0) ? BH_OFF : BX_OFF;
            for (int gi = 0; gi < 3; ++gi) {
                const float* W = WSET[s][gi];
                const int tile = TB[s][gi][0], nb = TB[s][gi][1];
                for (int dk = 0; dk < 2; ++dk) {
                    const int k = 2 * tid + dk;
                    const float* src = W + (size_t)k * H + F0;
                    const float4 a = *(const float4*)src;
                    const float4 bq = *(const float4*)(src + 4);
                    const float v[8] = {a.x, a.y, a.z, a.w, bq.x, bq.y, bq.z, bq.w};
#pragma unroll
                    for (int f = 0; f < 8; ++f)
                        *(unsigned short*)(smem + bbase + tile * 16384 +
                                           aswz(nb + f, k * 2)) = f2bf(v[f]);
                }
            }
        }
    }

    // ---- per-thread roles ----
    // h staging: member hm's record chunk hc (16 records = rows 2hc,2hc+1)
    const int hm = tid >> 2, hc = tid & 3;
    // x staging: row srow, 16 cols from scol
    const int srow = tid >> 5;
    const int scol = (tid & 31) * 16;
    // MFMA: wave w, lane: rc = A-row / B-col, kb = k-block
    const int w    = tid >> 6;
    const int lane = tid & 63;
    const int rc   = lane & 15;
    const int kb   = lane >> 4;
    int offk[4];
#pragma unroll
    for (int ks = 0; ks < 4; ++ks)
        offk[ks] = aswz(rc, (w * 4 + ks) * 64 + kb * 16);
    // epilogue: thread e<64 owns (batch em, feat ef); hold kept in-register
    const int em = tid >> 3, ef = tid & 7;
    float bzv = 0.f, brv = 0.f, bhv = 0.f, hold = 0.f;
    if (tid < 64) {
        bzv = bz[F0 + ef]; brv = br[F0 + ef]; bhv = bh[F0 + ef];
        hold = h0[(g * 8 + em) * H + F0 + ef];
        // publish initial record (stamp 0, parity 0); self-signaling, no drain
        const unsigned hi = f2bf(hold);
        const unsigned lo = f2bf(hold - bf2f((unsigned short)hi));
        const ull rec = ((ull)((hi << 16) | lo) << 32) | 0ull;
        __hip_atomic_store(&hgq[(((size_t)0 * 4 + g) * 64 + fc) * 64 + tid],
                           rec, __ATOMIC_RELAXED, __HIP_MEMORY_SCOPE_AGENT);
    }

    // prefetch x(0)
    float4 xr[4];
    {
        const float* xp = x + ((size_t)(g * 8 + srow) * L + 0) * D + scol;
#pragma unroll
        for (int c = 0; c < 4; ++c) xr[c] = *(const float4*)(xp + 4 * c);
    }

    for (int t = 0; t < L; ++t) {
        // ---- stage x(t) from prefetch regs (issued before the h poll) ----
        {
            float xv[16];
#pragma unroll
            for (int c = 0; c < 4; ++c) {
                xv[4 * c + 0] = xr[c].x; xv[4 * c + 1] = xr[c].y;
                xv[4 * c + 2] = xr[c].z; xv[4 * c + 3] = xr[c].w;
            }
#pragma unroll
            for (int gr = 0; gr < 2; ++gr) {
                uint4 phi, plo;
                const int ad = aswz(srow, scol * 2 + gr * 16);
                split8(xv + 8 * gr, phi, plo);
                *(uint4*)(smem + AX_HI + ad) = phi;
                *(uint4*)(smem + AX_LO + ad) = plo;
            }
        }

        // ---- poll h(t) records (stamp==t IS the barrier) + unpack ----
        {
            const ull* rb = hgq + (((size_t)(t & 1) * 4 + g) * 64 + hm) * 64 + hc * 16;
            ull q[16];
            for (;;) {
                bool ok = true;
#pragma unroll
                for (int i = 0; i < 16; ++i)
                    q[i] = __hip_atomic_load(rb + i, __ATOMIC_RELAXED,
                                             __HIP_MEMORY_SCOPE_AGENT);
#pragma unroll
                for (int i = 0; i < 16; ++i)
                    ok = ok && ((unsigned)q[i] == (unsigned)t);
                if (ok) break;
                __builtin_amdgcn_s_sleep(1);
            }
#pragma unroll
            for (int rsel = 0; rsel < 2; ++rsel) {
                const int b = 2 * hc + rsel;
                unsigned hv[8];
#pragma unroll
                for (int f = 0; f < 8; ++f)
                    hv[f] = (unsigned)(q[rsel * 8 + f] >> 32);
                uint4 hi4, lo4;
                hi4.x = (hv[0] >> 16) | (hv[1] & 0xFFFF0000u);
                hi4.y = (hv[2] >> 16) | (hv[3] & 0xFFFF0000u);
                hi4.z = (hv[4] >> 16) | (hv[5] & 0xFFFF0000u);
                hi4.w = (hv[6] >> 16) | (hv[7] & 0xFFFF0000u);
                lo4.x = (hv[0] & 0xFFFFu) | (hv[1] << 16);
                lo4.y = (hv[2] & 0xFFFFu) | (hv[3] << 16);
                lo4.z = (hv[4] & 0xFFFFu) | (hv[5] << 16);
                lo4.w = (hv[6] & 0xFFFFu) | (hv[7] << 16);
                const int ad = aswz(b, hm * 16);
                *(uint4*)(smem + AH_HI + ad) = hi4;
                *(uint4*)(smem + AH_LO + ad) = lo4;
            }
        }
        __syncthreads();

        // ---- MFMA: 4 passes (h_hi, h_lo, x_hi, x_lo) × 2 N-tiles ----
        f32x4 acc0 = {0.f, 0.f, 0.f, 0.f}, acc1 = {0.f, 0.f, 0.f, 0.f};
        {
            const char* Ab[4] = {smem + AH_HI, smem + AH_LO,
                                 smem + AX_HI, smem + AX_LO};
            const char* Bb[4] = {smem + BH_OFF, smem + BH_OFF,
                                 smem + BX_OFF, smem + BX_OFF};
#pragma unroll
            for (int p = 0; p < 4; ++p) {
#pragma unroll
                for (int ks = 0; ks < 4; ++ks) {
                    const short8v a  = *(const short8v*)(Ab[p] + offk[ks]);
                    const short8v b0 = *(const short8v*)(Bb[p] + offk[ks]);
                    const short8v b1 = *(const short8v*)(Bb[p] + 16384 + offk[ks]);
                    acc0 = __builtin_amdgcn_mfma_f32_16x16x32_bf16(a, b0, acc0, 0, 0, 0);
                    acc1 = __builtin_amdgcn_mfma_f32_16x16x32_bf16(a, b1, acc1, 0, 0, 0);
                }
            }
        }
        // write partial C (valid rows 0..7 live in lanes 0..31)
        if (lane < 32) {
            float* cbp = (float*)(smem + CB_OFF) + w * 272;
            const int mb = (lane >> 4) * 4, col = lane & 15;
#pragma unroll
            for (int reg = 0; reg < 4; ++reg) {
                cbp[(mb + reg) * 17 + col]       = acc0[reg];
                cbp[136 + (mb + reg) * 17 + col] = acc1[reg];
            }
        }
        __syncthreads();

        // ---- epilogue: 64 threads, one (batch, feature) each ----
        if (tid < 64) {
            float zz = 0.f, rr = 0.f, chh = 0.f, cxx = 0.f;
            const float* cb0 = (const float*)(smem + CB_OFF);
#pragma unroll
            for (int ww = 0; ww < 4; ++ww) {
                const float* cw = cb0 + ww * 272 + em * 17;
                zz  += cw[ef];        rr  += cw[8 + ef];
                chh += cw[136 + ef];  cxx += cw[136 + 8 + ef];
            }
            const float z = 1.f / (1.f + __expf(-(zz + bzv)));
            const float r = 1.f / (1.f + __expf(-(rr + brv)));
            const float pre = cxx + r * (chh + bhv);
            const float e = __expf(-2.f * fabsf(pre));
            float th = (1.f - e) / (1.f + e);
            th = (pre < 0.f) ? -th : th;
            const float hnv = z * hold + (1.f - z) * th;
            hold = hnv;

            // publish record: store depends on hnv -> cannot issue before the
            // staging loads that fed it returned; stamp rides in the same 8B.
            const unsigned hi = f2bf(hnv);
            const unsigned lo = f2bf(hnv - bf2f((unsigned short)hi));
            const ull rec = ((ull)((hi << 16) | lo) << 32) | (ull)(unsigned)(t + 1);
            __hip_atomic_store(&hgq[(((size_t)((t + 1) & 1) * 4 + g) * 64 + fc) * 64 + tid],
                               rec, __ATOMIC_RELAXED, __HIP_MEMORY_SCOPE_AGENT);

            // out writes off the critical path
            out[((size_t)(g * 8 + em) * L + t) * H + F0 + ef] = hnv;
            if (t == L - 1)
                out[(size_t)B * L * H + (size_t)(g * 8 + em) * H + F0 + ef] = hnv;
        }

        // prefetch x(t+1); latency hides under next step's poll
        if (t + 1 < L) {
            const float* xp = x + ((size_t)(g * 8 + srow) * L + (t + 1)) * D + scol;
#pragma unroll
            for (int c = 0; c < 4; ++c) xr[c] = *(const float4*)(xp + 4 * c);
        }
    }
}

extern "C" void kernel_launch(void* const* d_in, const int* in_sizes, int n_in,
                              void* d_out, int out_size, void* d_ws, size_t ws_size,
                              hipStream_t stream) {
    const float* x   = (const float*)d_in[0];
    const float* h0  = (const float*)d_in[1];
    const float* Wxz = (const float*)d_in[2];
    const float* Whz = (const float*)d_in[3];
    const float* bz  = (const float*)d_in[4];
    const float* Wxr = (const float*)d_in[5];
    const float* Whr = (const float*)d_in[6];
    const float* br  = (const float*)d_in[7];
    const float* Wxh = (const float*)d_in[8];
    const float* Whh = (const float*)d_in[9];
    const float* bh  = (const float*)d_in[10];
    float* out = (float*)d_out;
    ull* hgq = (ull*)d_ws;

    (void)hipFuncSetAttribute((const void*)gru_sys,
                              hipFuncAttributeMaxDynamicSharedMemorySize,
                              (int)SMEM_BYTES);

    void* args[] = {(void*)&x, (void*)&h0, (void*)&Wxz, (void*)&Whz, (void*)&bz,
                    (void*)&Wxr, (void*)&Whr, (void*)&br, (void*)&Wxh, (void*)&Whh,
                    (void*)&bh, (void*)&out, (void*)&hgq};
    hipError_t err = hipLaunchCooperativeKernel((void*)gru_sys, dim3(256),
                                                dim3(256), args,
                                                (unsigned)SMEM_BYTES, stream);
    if (err != hipSuccess) {
        // kernel uses only its own stamp protocol; 256 blocks at 1/CU are
        // trivially co-resident, so a plain launch is a safe fallback
        gru_sys<<<dim3(256), dim3(256), SMEM_BYTES, stream>>>(
            x, h0, Wxz, Whz, bz, Wxr, Whr, br, Wxh, Whh, bh, out, hgq);
    }
}

// Round 8
// 3625.629 us; speedup vs baseline: 1.5535x; 1.5535x over previous
//
#include <hip/hip_runtime.h>

constexpr int B = 32, L = 1024, D = 512, H = 512;

// ---- LDS byte offsets ----
// A tiles: [16 rows][512 k] bf16 (rows 8..15 permanently zero).
constexpr int AH_HI = 0;        // h hi
constexpr int AH_LO = 16384;    // h lo
constexpr int AX_OFF = 32768;   // x single bf16
// B tiles: [2 tiles][16 n][512 k] bf16. BH tile0=[Whz|Whr] tile1=[Whh|0];
// BX tile0=[Wxz|Wxr] tile1=[0|Wxh].
constexpr int BH_OFF = 49152;
constexpr int BX_OFF = 81920;
// C partials: [4 waves][2 tiles][8 m][17] f32
constexpr int CB_OFF = 114688;
constexpr size_t SMEM_BYTES = 119040;   // 116.25 KiB (proven territory)

// ---- workspace (dword offsets) ----
// hrec: [parity(2)][ring(4)][member(64)][64] u32 (hi16|lo16 bf16 of h)
constexpr int HREC_OFF = 0;          // 32768 dw = 128 KiB
constexpr int FLAGS_OFF = 32768;     // [ring(4)][member(64)] stride 32 dw

typedef __attribute__((ext_vector_type(8))) short short8v;
typedef __attribute__((ext_vector_type(4))) float f32x4;
using ull = unsigned long long;

__device__ __forceinline__ unsigned short f2bf(float f) {   // RNE f32->bf16
    unsigned u = __float_as_uint(f);
    return (unsigned short)((u + 0x7FFFu + ((u >> 16) & 1u)) >> 16);
}
__device__ __forceinline__ float bf2f(unsigned short b) {
    return __uint_as_float((unsigned)b << 16);
}
// XOR-swizzled byte address within a [row][1024B] tile
__device__ __forceinline__ int aswz(int row, int kbyte) {
    return row * 1024 + (kbyte ^ ((row & 7) << 4));
}

__global__ __launch_bounds__(256, 1)
void gru_rec(const float* __restrict__ x, const float* __restrict__ h0,
             const float* __restrict__ Wxz, const float* __restrict__ Whz,
             const float* __restrict__ bz,
             const float* __restrict__ Wxr, const float* __restrict__ Whr,
             const float* __restrict__ br,
             const float* __restrict__ Wxh, const float* __restrict__ Whh,
             const float* __restrict__ bh,
             float* __restrict__ out, unsigned* __restrict__ ws)
{
    extern __shared__ char smem[];

    const int tid = threadIdx.x;
    const int bid = blockIdx.x;
    // XCD-affinity remap (R5, kept): ring g occupies XCD residues {g, g+4}
    const int g  = bid & 3;          // ring: batches g*8 .. g*8+7
    const int fc = bid >> 2;         // member: features fc*8 .. +7
    const int F0 = fc * 8;

    unsigned* hrec  = ws + HREC_OFF;
    unsigned* flags = ws + FLAGS_OFF + g * 64 * 32;   // ring-local

    // ---- zero all LDS (A pad rows + B zero-blocks must stay zero) ----
    for (int i = tid; i < (int)(SMEM_BYTES / 16); i += 256)
        *(uint4*)(smem + i * 16) = make_uint4(0, 0, 0, 0);
    __syncthreads();

    // ---- one-time weight staging: bf16, swizzled [n][k] fragments ----
    {
        const float* WSET[2][3] = {{Whz, Whr, Whh}, {Wxz, Wxr, Wxh}};
        const int TB[2][3][2] = {{{0,0},{0,8},{1,0}}, {{0,0},{0,8},{1,8}}};
        for (int s = 0; s < 2; ++s) {
            const int bbase = (s == 0) ? BH_OFF : BX_OFF;
            for (int gi = 0; gi < 3; ++gi) {
                const float* W = WSET[s][gi];
                const int tile = TB[s][gi][0], nb = TB[s][gi][1];
                for (int dk = 0; dk < 2; ++dk) {
                    const int k = 2 * tid + dk;
                    const float* src = W + (size_t)k * H + F0;
                    const float4 a = *(const float4*)src;
                    const float4 bq = *(const float4*)(src + 4);
                    const float v[8] = {a.x, a.y, a.z, a.w, bq.x, bq.y, bq.z, bq.w};
#pragma unroll
                    for (int f = 0; f < 8; ++f)
                        *(unsigned short*)(smem + bbase + tile * 16384 +
                                           aswz(nb + f, k * 2)) = f2bf(v[f]);
                }
            }
        }
    }

    // ---- per-thread roles ----
    // x staging: row srow = tid&7 (bank-spread), 16 cols from scol
    const int srow = tid & 7;
    const int scol = (tid >> 3) * 16;
    // h staging: member hm = tid>>2, quarter q = tid&3 (16 records = 2 rows)
    const int hm = tid >> 2, hq = tid & 3;
    // MFMA: wave w, lane: rc = A-row / B-col, kb = k-block
    const int w    = tid >> 6;
    const int lane = tid & 63;
    const int rc   = lane & 15;
    const int kb   = lane >> 4;
    int offk[4];
#pragma unroll
    for (int ks = 0; ks < 4; ++ks)
        offk[ks] = aswz(rc, (w * 4 + ks) * 64 + kb * 16);
    // epilogue (wave 0): thread owns (batch em, feat ef); hold kept in-register
    const int em = tid >> 3, ef = tid & 7;
    float bzv = 0.f, brv = 0.f, bhv = 0.f, hold = 0.f;
    if (tid < 64) {
        bzv = bz[F0 + ef]; brv = br[F0 + ef]; bhv = bh[F0 + ef];
        hold = h0[(g * 8 + em) * H + F0 + ef];
        // publish initial packed record (parity 0), then drain + flag=1
        const unsigned hi = f2bf(hold);
        const unsigned lo = f2bf(hold - bf2f((unsigned short)hi));
        __hip_atomic_store(&hrec[((0 * 4 + g) * 64 + fc) * 64 + tid],
                           (hi << 16) | lo, __ATOMIC_RELAXED,
                           __HIP_MEMORY_SCOPE_AGENT);
        asm volatile("s_waitcnt vmcnt(0)" ::: "memory");
        if (tid == 0)
            __hip_atomic_store(&flags[fc * 32], 1u, __ATOMIC_RELAXED,
                               __HIP_MEMORY_SCOPE_AGENT);
    }

    // prefetch x(0)
    float4 xr[4];
    {
        const float* xp = x + ((size_t)(g * 8 + srow) * L + 0) * D + scol;
#pragma unroll
        for (int c = 0; c < 4; ++c) xr[c] = *(const float4*)(xp + 4 * c);
    }

    for (int t = 0; t < L; ++t) {
        // ---- stage x(t) as single bf16 (before the poll; hides LDS work) ----
        {
            float xv[16];
#pragma unroll
            for (int c = 0; c < 4; ++c) {
                xv[4 * c + 0] = xr[c].x; xv[4 * c + 1] = xr[c].y;
                xv[4 * c + 2] = xr[c].z; xv[4 * c + 3] = xr[c].w;
            }
            unsigned wd[8];
#pragma unroll
            for (int j = 0; j < 8; ++j)
                wd[j] = (unsigned)f2bf(xv[2 * j]) |
                        ((unsigned)f2bf(xv[2 * j + 1]) << 16);
            *(uint4*)(smem + AX_OFF + aswz(srow, scol * 2)) =
                make_uint4(wd[0], wd[1], wd[2], wd[3]);
            *(uint4*)(smem + AX_OFF + aswz(srow, scol * 2 + 16)) =
                make_uint4(wd[4], wd[5], wd[6], wd[7]);
        }

        // ---- wave-0 poll: all 64 members' flags in {t+1, t+2} ----
        const unsigned stamp = (unsigned)(t + 1);
        if (tid < 64) {
            unsigned v;
            do {
                v = __hip_atomic_load(&flags[tid * 32], __ATOMIC_RELAXED,
                                      __HIP_MEMORY_SCOPE_AGENT);
                if (__all((v - stamp) <= 1u)) break;
                __builtin_amdgcn_s_sleep(1);
            } while (true);
        }
        __syncthreads();

        // ---- stage h(t): bulk-load packed records once, bit-unpack to LDS ----
        {
            const ull* rb = (const ull*)&hrec[(((t & 1) * 4 + g) * 64 + hm) * 64] + hq * 8;
            ull qd[8];
#pragma unroll
            for (int i = 0; i < 8; ++i)
                qd[i] = __hip_atomic_load(rb + i, __ATOMIC_RELAXED,
                                          __HIP_MEMORY_SCOPE_AGENT);
#pragma unroll
            for (int rsel = 0; rsel < 2; ++rsel) {
                const int brow = 2 * hq + rsel;
                unsigned v[8];
#pragma unroll
                for (int f = 0; f < 8; ++f) {
                    const ull qq = qd[rsel * 4 + (f >> 1)];
                    v[f] = (f & 1) ? (unsigned)(qq >> 32) : (unsigned)qq;
                }
                uint4 hi4, lo4;
                hi4.x = (v[0] >> 16) | (v[1] & 0xFFFF0000u);
                hi4.y = (v[2] >> 16) | (v[3] & 0xFFFF0000u);
                hi4.z = (v[4] >> 16) | (v[5] & 0xFFFF0000u);
                hi4.w = (v[6] >> 16) | (v[7] & 0xFFFF0000u);
                lo4.x = (v[0] & 0xFFFFu) | (v[1] << 16);
                lo4.y = (v[2] & 0xFFFFu) | (v[3] << 16);
                lo4.z = (v[4] & 0xFFFFu) | (v[5] << 16);
                lo4.w = (v[6] & 0xFFFFu) | (v[7] << 16);
                const int ad = aswz(brow, hm * 16);
                *(uint4*)(smem + AH_HI + ad) = hi4;
                *(uint4*)(smem + AH_LO + ad) = lo4;
            }
        }
        __syncthreads();

        // ---- MFMA: 3 passes (h_hi, h_lo, x) × 2 N-tiles × 4 k-steps ----
        f32x4 acc0 = {0.f, 0.f, 0.f, 0.f}, acc1 = {0.f, 0.f, 0.f, 0.f};
        {
            const char* Ab[3] = {smem + AH_HI, smem + AH_LO, smem + AX_OFF};
            const char* Bb[3] = {smem + BH_OFF, smem + BH_OFF, smem + BX_OFF};
#pragma unroll
            for (int p = 0; p < 3; ++p) {
#pragma unroll
                for (int ks = 0; ks < 4; ++ks) {
                    const short8v a  = *(const short8v*)(Ab[p] + offk[ks]);
                    const short8v b0 = *(const short8v*)(Bb[p] + offk[ks]);
                    const short8v b1 = *(const short8v*)(Bb[p] + 16384 + offk[ks]);
                    acc0 = __builtin_amdgcn_mfma_f32_16x16x32_bf16(a, b0, acc0, 0, 0, 0);
                    acc1 = __builtin_amdgcn_mfma_f32_16x16x32_bf16(a, b1, acc1, 0, 0, 0);
                }
            }
        }
        // write partial C (valid rows 0..7 live in lanes 0..31)
        if (lane < 32) {
            float* cbp = (float*)(smem + CB_OFF) + w * 272;
            const int mb = (lane >> 4) * 4, col = lane & 15;
#pragma unroll
            for (int reg = 0; reg < 4; ++reg) {
                cbp[(mb + reg) * 17 + col]       = acc0[reg];
                cbp[136 + (mb + reg) * 17 + col] = acc1[reg];
            }
        }
        __syncthreads();

        // ---- epilogue (wave 0 only): combine, gates, publish record+flag ----
        float hnv = 0.f;
        if (tid < 64) {
            float zz = 0.f, rr = 0.f, chh = 0.f, cxx = 0.f;
            const float* cb0 = (const float*)(smem + CB_OFF);
#pragma unroll
            for (int ww = 0; ww < 4; ++ww) {
                const float* cw = cb0 + ww * 272 + em * 17;
                zz  += cw[ef];        rr  += cw[8 + ef];
                chh += cw[136 + ef];  cxx += cw[136 + 8 + ef];
            }
            const float z = 1.f / (1.f + __expf(-(zz + bzv)));
            const float r = 1.f / (1.f + __expf(-(rr + brv)));
            const float pre = cxx + r * (chh + bhv);
            const float e = __expf(-2.f * fabsf(pre));
            float th = (1.f - e) / (1.f + e);
            th = (pre < 0.f) ? -th : th;
            hnv = z * hold + (1.f - z) * th;
            hold = hnv;

            // packed record store -> wave-0 drain -> flag (early publish; no
            // block-wide sync: only wave 0's h-records guard the flag)
            const unsigned hi = f2bf(hnv);
            const unsigned lo = f2bf(hnv - bf2f((unsigned short)hi));
            __hip_atomic_store(&hrec[((((t + 1) & 1) * 4 + g) * 64 + fc) * 64 + tid],
                               (hi << 16) | lo, __ATOMIC_RELAXED,
                               __HIP_MEMORY_SCOPE_AGENT);
            asm volatile("s_waitcnt vmcnt(0)" ::: "memory");
            if (tid == 0)
                __hip_atomic_store(&flags[fc * 32], stamp + 1u, __ATOMIC_RELAXED,
                                   __HIP_MEMORY_SCOPE_AGENT);

            // out writes off the critical path
            out[((size_t)(g * 8 + em) * L + t) * H + F0 + ef] = hnv;
            if (t == L - 1)
                out[(size_t)B * L * H + (size_t)(g * 8 + em) * H + F0 + ef] = hnv;
        }

        // prefetch x(t+1); latency hides under next step's poll
        if (t + 1 < L) {
            const float* xp = x + ((size_t)(g * 8 + srow) * L + (t + 1)) * D + scol;
#pragma unroll
            for (int c = 0; c < 4; ++c) xr[c] = *(const float4*)(xp + 4 * c);
        }
        // NOTE: no 4th sync needed — next x-stage writes AX, which this
        // iteration's MFMA finished reading before the C-sync above; wave 0's
        // epilogue touches only CB/regs/global.
    }
}

extern "C" void kernel_launch(void* const* d_in, const int* in_sizes, int n_in,
                              void* d_out, int out_size, void* d_ws, size_t ws_size,
                              hipStream_t stream) {
    const float* x   = (const float*)d_in[0];
    const float* h0  = (const float*)d_in[1];
    const float* Wxz = (const float*)d_in[2];
    const float* Whz = (const float*)d_in[3];
    const float* bz  = (const float*)d_in[4];
    const float* Wxr = (const float*)d_in[5];
    const float* Whr = (const float*)d_in[6];
    const float* br  = (const float*)d_in[7];
    const float* Wxh = (const float*)d_in[8];
    const float* Whh = (const float*)d_in[9];
    const float* bh  = (const float*)d_in[10];
    float* out = (float*)d_out;
    unsigned* ws = (unsigned*)d_ws;

    (void)hipFuncSetAttribute((const void*)gru_rec,
                              hipFuncAttributeMaxDynamicSharedMemorySize,
                              (int)SMEM_BYTES);

    void* args[] = {(void*)&x, (void*)&h0, (void*)&Wxz, (void*)&Whz, (void*)&bz,
                    (void*)&Wxr, (void*)&Whr, (void*)&br, (void*)&Wxh, (void*)&Whh,
                    (void*)&bh, (void*)&out, (void*)&ws};
    hipError_t err = hipLaunchCooperativeKernel((void*)gru_rec, dim3(256),
                                                dim3(256), args,
                                                (unsigned)SMEM_BYTES, stream);
    if (err != hipSuccess) {
        // kernel uses only its own flag barrier; 256 blocks at 1/CU are
        // trivially co-resident, so a plain launch is a safe fallback
        gru_rec<<<dim3(256), dim3(256), SMEM_BYTES, stream>>>(
            x, h0, Wxz, Whz, bz, Wxr, Whr, br, Wxh, Whh, bh, out, ws);
    }
}